// Round 11
// baseline (1924.859 us; speedup 1.0000x reference)
//
#include <hip/hip_runtime.h>

// zhannRNN: x[8,512,512] -> xp GEMM -> 512-step tanh recurrence (HID=2048) -> out GEMM [*,128]
//   Phase 0: fill hs with sentinel 0xFF80FF80 (-Inf bf16; impossible as tanh output)
//   Phase 1: xp[t][b][j] = x @ W_ih^T + b_ih + b_hh      (bf16 MFMA GEMM)
//   Phase 2: persistent scan, 32 wgs x 512 thr. hs STEP-MAJOR [t][b][j] (contiguous 32KB
//            per step). Sentinel data-poll w/ selective re-poll + split vmcnt first pass;
//            wave-0-only epilogue with 64x dwordx4 packed stores (fast drain).
//   Phase 3: out = hs @ W_out^T + b_out  (A rows are m=t*8+b; epilogue remaps to b*512+t)

#define IN_K   512
#define HID    2048
#define OUTN   128
#define BB     8
#define TSTEPS 512
#define NWG    32
#define JPW    64
#define SENT   0xFF80FF80u

typedef __bf16 bf16x8 __attribute__((ext_vector_type(8)));
typedef unsigned short u16x8 __attribute__((ext_vector_type(8)));
typedef unsigned int u32x4 __attribute__((ext_vector_type(4)));
typedef float f32v4 __attribute__((ext_vector_type(4)));

union Frag8 { u16x8 u; bf16x8 b; u32x4 d; };

__device__ __forceinline__ unsigned short f2bf(float f) {
  unsigned int u = __float_as_uint(f);
  return (unsigned short)((u + 0x7FFFu + ((u >> 16) & 1u)) >> 16);  // RNE
}

__device__ __forceinline__ float tanh_fast(float x) {
  return 1.0f - 2.0f / (__expf(2.0f * x) + 1.0f);  // ~1e-6 abs err, << bf16 rounding
}

// ---------------- Phase 0: sentinel fill ----------------
__global__ __launch_bounds__(256)
void sentinel_kernel(u32x4* __restrict__ p) {
  const size_t i = (size_t)blockIdx.x * 256 + threadIdx.x;
  u32x4 v; v[0] = SENT; v[1] = SENT; v[2] = SENT; v[3] = SENT;
  p[i] = v;
}

// ---------------- GEMM (phases 1 & 3) ----------------
template<int EPI>
__global__ __launch_bounds__(256, 2)
void gemm_kernel(const void* __restrict__ Aptr, const float* __restrict__ Bptr,
                 const float* __restrict__ bias0, const float* __restrict__ bias1,
                 float* __restrict__ Cout, const int Kdim, const int Ndim)
{
  __shared__ __align__(16) unsigned short As[64][56];
  __shared__ __align__(16) unsigned short Bs[64][56];

  const int m0 = blockIdx.x * 64;
  const int n0 = blockIdx.y * 64;
  const int tid = threadIdx.x;
  const int w = tid >> 6, l = tid & 63;
  const int l15 = l & 15, lk = (l >> 4) * 8;
  const int wm = (w >> 1) * 32, wn = (w & 1) * 32;

  f32v4 acc[2][2];
  #pragma unroll
  for (int mt = 0; mt < 2; ++mt)
    #pragma unroll
    for (int nt = 0; nt < 2; ++nt)
      #pragma unroll
      for (int r = 0; r < 4; ++r) acc[mt][nt][r] = 0.0f;

  for (int k0 = 0; k0 < Kdim; k0 += 32) {
    __syncthreads();
    if (EPI == 0) {
      const float* A = (const float*)Aptr;
      const int r = tid >> 3, c4 = (tid & 7) * 4;
      #pragma unroll
      for (int it = 0; it < 2; ++it) {
        const float4 v = *(const float4*)(A + (size_t)(m0 + r + it * 32) * Kdim + k0 + c4);
        unsigned short* d = &As[r + it * 32][c4];
        d[0] = f2bf(v.x); d[1] = f2bf(v.y); d[2] = f2bf(v.z); d[3] = f2bf(v.w);
      }
    } else {
      const unsigned short* A = (const unsigned short*)Aptr;
      const int r = tid >> 2, c8 = (tid & 3) * 8;
      const u16x8 v = *(const u16x8*)(A + (size_t)(m0 + r) * Kdim + k0 + c8);
      *(u16x8*)&As[r][c8] = v;
    }
    {
      const int r = tid >> 3, c4 = (tid & 7) * 4;
      #pragma unroll
      for (int it = 0; it < 2; ++it) {
        const float4 v = *(const float4*)(Bptr + (size_t)(n0 + r + it * 32) * Kdim + k0 + c4);
        unsigned short* d = &Bs[r + it * 32][c4];
        d[0] = f2bf(v.x); d[1] = f2bf(v.y); d[2] = f2bf(v.z); d[3] = f2bf(v.w);
      }
    }
    __syncthreads();

    Frag8 af[2], bg[2];
    #pragma unroll
    for (int mt = 0; mt < 2; ++mt) af[mt].u = *(const u16x8*)&As[wm + mt * 16 + l15][lk];
    #pragma unroll
    for (int nt = 0; nt < 2; ++nt) bg[nt].u = *(const u16x8*)&Bs[wn + nt * 16 + l15][lk];
    #pragma unroll
    for (int mt = 0; mt < 2; ++mt)
      #pragma unroll
      for (int nt = 0; nt < 2; ++nt)
        acc[mt][nt] = __builtin_amdgcn_mfma_f32_16x16x32_bf16(af[mt].b, bg[nt].b, acc[mt][nt], 0, 0, 0);
  }

  #pragma unroll
  for (int mt = 0; mt < 2; ++mt)
    #pragma unroll
    for (int nt = 0; nt < 2; ++nt)
      #pragma unroll
      for (int r = 0; r < 4; ++r) {
        const int m = m0 + wm + mt * 16 + (l >> 4) * 4 + r;
        const int n = n0 + wn + nt * 16 + l15;
        float v = acc[mt][nt][r];
        if (EPI == 0) {
          v += bias0[n] + bias1[n];
          const int b = m >> 9, t = m & 511;
          Cout[((size_t)t * BB + b) * Ndim + n] = v;       // xp[t][b][n]
        } else {
          v += bias0[n];
          const int b = m & 7, t = m >> 3;                  // A row was t*8+b
          Cout[((size_t)b * TSTEPS + t) * Ndim + n] = v;    // out[b][t][n]
        }
      }
}

// ---------------- Phase 2: step-major sentinel scan ----------------
__global__ __launch_bounds__(512, 2)
void scan_kernel(const float* __restrict__ Whh, const float* __restrict__ xp,
                 unsigned short* __restrict__ hs)
{
  const int g = blockIdx.x;
  const int tid = threadIdx.x;
  const int w = tid >> 6, l = tid & 63;     // wave w in [0,8): K-chunk [w*256, w*256+256)
  const int l15 = l & 15, lk = (l >> 4) * 8;
  const int jbase = g * JPW;                // wg owns j in [jbase, jbase+64)

  // Preload W_hh slice: Bw[jt][kc], j = jbase+jt*16+l15, k = w*256+kc*32+lk  (128 VGPRs)
  Frag8 Bw[4][8];
  #pragma unroll
  for (int jt = 0; jt < 4; ++jt) {
    const int j = jbase + jt * 16 + l15;
    #pragma unroll
    for (int kc = 0; kc < 8; ++kc) {
      const int k = w * 256 + kc * 32 + lk;
      const float4* p = (const float4*)(Whh + (size_t)j * HID + k);
      const float4 u0 = p[0], u1 = p[1];
      Frag8 f;
      f.u[0] = f2bf(u0.x); f.u[1] = f2bf(u0.y); f.u[2] = f2bf(u0.z); f.u[3] = f2bf(u0.w);
      f.u[4] = f2bf(u1.x); f.u[5] = f2bf(u1.y); f.u[6] = f2bf(u1.z); f.u[7] = f2bf(u1.w);
      Bw[jt][kc] = f;
    }
  }

  __shared__ float red[8][4][16][17];  // +1 pad: single-wave epilogue stays <=4-way conflict
  const int arow = l15 & 7;            // A rows 8..15 duplicate 0..7 (same addr -> coalesced)
  const int eb = (tid & 63) >> 3;      // epilogue (wave 0): batch
  const int eq = tid & 7;              // epilogue: j-group of 8
  const int ejt = eq >> 1;             // j-tile index
  const int ecol = (eq & 1) * 8;       // col base within tile

#define CHECK_MFMA(kc) do {                                                    \
    unsigned int mv = min(min(a[kc].d[0] ^ SENT, a[kc].d[1] ^ SENT),           \
                          min(a[kc].d[2] ^ SENT, a[kc].d[3] ^ SENT));          \
    if (__all(mv != 0u)) {                                                     \
      valid |= (1u << (kc));                                                   \
      _Pragma("unroll") for (int jt = 0; jt < 4; ++jt)                         \
        acc[jt] = __builtin_amdgcn_mfma_f32_16x16x32_bf16(a[kc].b,             \
                      Bw[jt][(kc)].b, acc[jt], 0, 0, 0);                       \
    }                                                                          \
  } while (0)

  for (int t = 0; t < TSTEPS; ++t) {
    // xp: early issue (inline asm so it cannot sink past the poll), wave 0 only
    u32x4 xr0, xr1;
    if (tid < 64) {
      const float* xq = xp + ((size_t)t * BB + eb) * HID + jbase + eq * 8;
      asm volatile("global_load_dwordx4 %0, %2, off\n\t"
                   "global_load_dwordx4 %1, %2, off offset:16"
                   : "=v"(xr0), "=v"(xr1) : "v"(xq));
    }

    f32v4 acc[4];
    #pragma unroll
    for (int jt = 0; jt < 4; ++jt)
      #pragma unroll
      for (int r = 0; r < 4; ++r) acc[jt][r] = 0.f;

    if (t > 0) {  // h_{-1} == 0
      const unsigned short* hb = hs + ((size_t)(t - 1) * BB + arow) * HID + w * 256 + lk;
      Frag8 a[8];
      unsigned int valid = 0;
      // first pass: issue all 8, split-wait (check 0-3 while 4-7 in flight)
      #pragma unroll
      for (int kc = 0; kc < 8; ++kc)
        asm volatile("global_load_dwordx4 %0, %1, off offset:%2 sc0 sc1"
                     : "=v"(a[kc].d) : "v"(hb), "n"(kc * 64));
      asm volatile("s_waitcnt vmcnt(4)" ::: "memory");
      __builtin_amdgcn_sched_barrier(0);
      #pragma unroll
      for (int kc = 0; kc < 4; ++kc) CHECK_MFMA(kc);
      asm volatile("s_waitcnt vmcnt(0)" ::: "memory");
      __builtin_amdgcn_sched_barrier(0);
      #pragma unroll
      for (int kc = 4; kc < 8; ++kc) CHECK_MFMA(kc);
      // straggler loop: selective re-poll
      while (valid != 0xFFu) {
        #pragma unroll
        for (int kc = 0; kc < 8; ++kc)
          if (!(valid & (1u << kc)))
            asm volatile("global_load_dwordx4 %0, %1, off offset:%2 sc0 sc1"
                         : "=v"(a[kc].d) : "v"(hb), "n"(kc * 64));
        asm volatile("s_waitcnt vmcnt(0)" ::: "memory");
        __builtin_amdgcn_sched_barrier(0);
        #pragma unroll
        for (int kc = 0; kc < 8; ++kc)
          if (!(valid & (1u << kc))) CHECK_MFMA(kc);
      }
    }

    // cross-wave K-reduction via LDS
    #pragma unroll
    for (int jt = 0; jt < 4; ++jt)
      #pragma unroll
      for (int r = 0; r < 4; ++r)
        red[w][jt][(l >> 4) * 4 + r][l15] = acc[jt][r];
    __syncthreads();

    if (tid < 64) {  // wave-0-only epilogue: 8 j per lane, one dwordx4 store
      asm volatile("s_waitcnt vmcnt(0)" ::: "memory");  // xr arrival (t==0 path)
      __builtin_amdgcn_sched_barrier(0);
      float xv[8];
      xv[0] = __uint_as_float(xr0[0]); xv[1] = __uint_as_float(xr0[1]);
      xv[2] = __uint_as_float(xr0[2]); xv[3] = __uint_as_float(xr0[3]);
      xv[4] = __uint_as_float(xr1[0]); xv[5] = __uint_as_float(xr1[1]);
      xv[6] = __uint_as_float(xr1[2]); xv[7] = __uint_as_float(xr1[3]);
      u32x4 pk;
      #pragma unroll
      for (int i2 = 0; i2 < 4; ++i2) {
        float s0 = xv[i2 * 2], s1 = xv[i2 * 2 + 1];
        #pragma unroll
        for (int wv = 0; wv < 8; ++wv) {
          s0 += red[wv][ejt][eb][ecol + i2 * 2];
          s1 += red[wv][ejt][eb][ecol + i2 * 2 + 1];
        }
        pk[i2] = (unsigned int)f2bf(tanh_fast(s0))
               | ((unsigned int)f2bf(tanh_fast(s1)) << 16);
      }
      unsigned short* hp = hs + ((size_t)t * BB + eb) * HID + jbase + eq * 8;
      asm volatile("global_store_dwordx4 %0, %1, off sc0 sc1" :: "v"(hp), "v"(pk) : "memory");
    }
    __syncthreads();  // red[] reuse guard
  }
#undef CHECK_MFMA
}

extern "C" void kernel_launch(void* const* d_in, const int* in_sizes, int n_in,
                              void* d_out, int out_size, void* d_ws, size_t ws_size,
                              hipStream_t stream)
{
  (void)in_sizes; (void)n_in; (void)out_size; (void)ws_size;
  const float* x    = (const float*)d_in[0];
  const float* Wih  = (const float*)d_in[1];
  const float* bih  = (const float*)d_in[2];
  const float* Whh  = (const float*)d_in[3];
  const float* bhh  = (const float*)d_in[4];
  const float* Wout = (const float*)d_in[5];
  const float* bout = (const float*)d_in[6];
  float* out = (float*)d_out;

  char* ws = (char*)d_ws;
  float* xp          = (float*)(ws);                                // [512][8][2048] fp32, 32 MiB
  unsigned short* hs = (unsigned short*)(ws + (size_t)(32 << 20));  // [512][8][2048] bf16 STEP-MAJOR, 16 MiB

  // Phase 0: sentinel-fill hs
  sentinel_kernel<<<dim3(4096), 256, 0, stream>>>((u32x4*)hs);
  // Phase 1: xp = x @ W_ih^T + b_ih + b_hh
  gemm_kernel<0><<<dim3(64, 32), 256, 0, stream>>>(x, Wih, bih, bhh, xp, IN_K, HID);
  // Phase 2: barrier-free sequential scan
  scan_kernel<<<dim3(NWG), 512, 0, stream>>>(Whh, xp, hs);
  // Phase 3: out = hs @ W_out^T + b_out (A rows = t*8+b)
  gemm_kernel<1><<<dim3(64, 2), 256, 0, stream>>>(hs, Wout, bout, nullptr, out, HID, OUTN);
}

// Round 12
// 1772.221 us; speedup vs baseline: 1.0861x; 1.0861x over previous
//
#include <hip/hip_runtime.h>

// zhannRNN: x[8,512,512] -> xp GEMM -> 512-step tanh recurrence (HID=2048) -> out GEMM [*,128]
//   Phase 0: fill hs with sentinel 0xFF80FF80 (-Inf bf16; impossible as tanh output)
//   Phase 1: xp[t][b][j] = x @ W_ih^T + b_ih + b_hh      (bf16 MFMA GEMM)
//   Phase 2: persistent scan, 32 wgs x 512 thr (R10 structure). Sentinel data-poll,
//            selective re-poll, incremental MFMA. NEW: h-store + xp-prefetch issued
//            AFTER the trailing barrier so their ACKs drain inside the NEXT step's
//            poll vmcnt(0) (store-ACK off the serial path; barriers no longer stall on WT ACK).
//   Phase 3: out = hs @ W_out^T + b_out                   (bf16 MFMA GEMM)

#define IN_K   512
#define HID    2048
#define OUTN   128
#define BB     8
#define TSTEPS 512
#define NWG    32
#define JPW    64
#define SENT   0xFF80FF80u

typedef __bf16 bf16x8 __attribute__((ext_vector_type(8)));
typedef unsigned short u16x8 __attribute__((ext_vector_type(8)));
typedef unsigned int u32x4 __attribute__((ext_vector_type(4)));
typedef unsigned int u32x2 __attribute__((ext_vector_type(2)));
typedef float f32v4 __attribute__((ext_vector_type(4)));

union Frag8 { u16x8 u; bf16x8 b; u32x4 d; };

__device__ __forceinline__ unsigned short f2bf(float f) {
  unsigned int u = __float_as_uint(f);
  return (unsigned short)((u + 0x7FFFu + ((u >> 16) & 1u)) >> 16);  // RNE
}

__device__ __forceinline__ float tanh_fast(float x) {
  return 1.0f - 2.0f / (__expf(2.0f * x) + 1.0f);  // ~1e-6 abs err, << bf16 rounding
}

// ---------------- Phase 0: sentinel fill ----------------
__global__ __launch_bounds__(256)
void sentinel_kernel(u32x4* __restrict__ p) {
  const size_t i = (size_t)blockIdx.x * 256 + threadIdx.x;
  u32x4 v; v[0] = SENT; v[1] = SENT; v[2] = SENT; v[3] = SENT;
  p[i] = v;
}

// ---------------- GEMM (phases 1 & 3) ----------------
template<int EPI>
__global__ __launch_bounds__(256, 2)
void gemm_kernel(const void* __restrict__ Aptr, const float* __restrict__ Bptr,
                 const float* __restrict__ bias0, const float* __restrict__ bias1,
                 float* __restrict__ Cout, const int Kdim, const int Ndim)
{
  __shared__ __align__(16) unsigned short As[64][56];
  __shared__ __align__(16) unsigned short Bs[64][56];

  const int m0 = blockIdx.x * 64;
  const int n0 = blockIdx.y * 64;
  const int tid = threadIdx.x;
  const int w = tid >> 6, l = tid & 63;
  const int l15 = l & 15, lk = (l >> 4) * 8;
  const int wm = (w >> 1) * 32, wn = (w & 1) * 32;

  f32v4 acc[2][2];
  #pragma unroll
  for (int mt = 0; mt < 2; ++mt)
    #pragma unroll
    for (int nt = 0; nt < 2; ++nt)
      #pragma unroll
      for (int r = 0; r < 4; ++r) acc[mt][nt][r] = 0.0f;

  for (int k0 = 0; k0 < Kdim; k0 += 32) {
    __syncthreads();
    if (EPI == 0) {
      const float* A = (const float*)Aptr;
      const int r = tid >> 3, c4 = (tid & 7) * 4;
      #pragma unroll
      for (int it = 0; it < 2; ++it) {
        const float4 v = *(const float4*)(A + (size_t)(m0 + r + it * 32) * Kdim + k0 + c4);
        unsigned short* d = &As[r + it * 32][c4];
        d[0] = f2bf(v.x); d[1] = f2bf(v.y); d[2] = f2bf(v.z); d[3] = f2bf(v.w);
      }
    } else {
      const unsigned short* A = (const unsigned short*)Aptr;
      const int r = tid >> 2, c8 = (tid & 3) * 8;
      const u16x8 v = *(const u16x8*)(A + (size_t)(m0 + r) * Kdim + k0 + c8);
      *(u16x8*)&As[r][c8] = v;
    }
    {
      const int r = tid >> 3, c4 = (tid & 7) * 4;
      #pragma unroll
      for (int it = 0; it < 2; ++it) {
        const float4 v = *(const float4*)(Bptr + (size_t)(n0 + r + it * 32) * Kdim + k0 + c4);
        unsigned short* d = &Bs[r + it * 32][c4];
        d[0] = f2bf(v.x); d[1] = f2bf(v.y); d[2] = f2bf(v.z); d[3] = f2bf(v.w);
      }
    }
    __syncthreads();

    Frag8 af[2], bg[2];
    #pragma unroll
    for (int mt = 0; mt < 2; ++mt) af[mt].u = *(const u16x8*)&As[wm + mt * 16 + l15][lk];
    #pragma unroll
    for (int nt = 0; nt < 2; ++nt) bg[nt].u = *(const u16x8*)&Bs[wn + nt * 16 + l15][lk];
    #pragma unroll
    for (int mt = 0; mt < 2; ++mt)
      #pragma unroll
      for (int nt = 0; nt < 2; ++nt)
        acc[mt][nt] = __builtin_amdgcn_mfma_f32_16x16x32_bf16(af[mt].b, bg[nt].b, acc[mt][nt], 0, 0, 0);
  }

  #pragma unroll
  for (int mt = 0; mt < 2; ++mt)
    #pragma unroll
    for (int nt = 0; nt < 2; ++nt)
      #pragma unroll
      for (int r = 0; r < 4; ++r) {
        const int m = m0 + wm + mt * 16 + (l >> 4) * 4 + r;
        const int n = n0 + wn + nt * 16 + l15;
        float v = acc[mt][nt][r];
        if (EPI == 0) {
          v += bias0[n] + bias1[n];
          const int b = m >> 9, t = m & 511;
          Cout[((size_t)t * BB + b) * Ndim + n] = v;
        } else {
          v += bias0[n];
          Cout[(size_t)m * Ndim + n] = v;
        }
      }
}

// ---------------- Phase 2: 32wg x 8-wave sentinel scan, deferred-store ----------------
__global__ __launch_bounds__(512, 2)
void scan_kernel(const float* __restrict__ Whh, const float* __restrict__ xp,
                 unsigned short* __restrict__ hs)
{
  const int g = blockIdx.x;
  const int tid = threadIdx.x;
  const int w = tid >> 6, l = tid & 63;     // wave w in [0,8): K-chunk [w*256, w*256+256)
  const int l15 = l & 15, lk = (l >> 4) * 8;
  const int jbase = g * JPW;                // wg owns j in [jbase, jbase+64)

  // Preload W_hh slice: Bw[jt][kc], j = jbase+jt*16+l15, k = w*256+kc*32+lk  (128 VGPRs)
  Frag8 Bw[4][8];
  #pragma unroll
  for (int jt = 0; jt < 4; ++jt) {
    const int j = jbase + jt * 16 + l15;
    #pragma unroll
    for (int kc = 0; kc < 8; ++kc) {
      const int k = w * 256 + kc * 32 + lk;
      const float4* p = (const float4*)(Whh + (size_t)j * HID + k);
      const float4 u0 = p[0], u1 = p[1];
      Frag8 f;
      f.u[0] = f2bf(u0.x); f.u[1] = f2bf(u0.y); f.u[2] = f2bf(u0.z); f.u[3] = f2bf(u0.w);
      f.u[4] = f2bf(u1.x); f.u[5] = f2bf(u1.y); f.u[6] = f2bf(u1.z); f.u[7] = f2bf(u1.w);
      Bw[jt][kc] = f;
    }
  }

  __shared__ float red[8][4][16][16];  // 8 waves x 4 j-tiles x 16x16, 32KB
  const int om = tid >> 5;             // (tid<256) batch index
  const int oj2 = (tid & 31) * 2;      // j-offset pair within wg
  const int jt_e = oj2 >> 4, col = oj2 & 15;
  const int arow = l15 & 7;            // A rows 8..15 duplicate 0..7 (same addr -> coalesced)

  // epilogue xp value for step t, prefetched one step ahead (asm so it can't sink)
  u32x2 xr;
  if (tid < 256) {
    const float* xq = xp + (size_t)om * HID + jbase + oj2;   // t = 0
    asm volatile("global_load_dwordx2 %0, %1, off" : "=v"(xr) : "v"(xq));
  }
  asm volatile("s_waitcnt vmcnt(0)" ::: "memory");  // one-time: xr ready for t=0
  __builtin_amdgcn_sched_barrier(0);

  for (int t = 0; t < TSTEPS; ++t) {
    f32v4 acc[4];
    #pragma unroll
    for (int jt = 0; jt < 4; ++jt)
      #pragma unroll
      for (int r = 0; r < 4; ++r) acc[jt][r] = 0.f;

    if (t > 0) {  // h_{-1} == 0
      const unsigned short* hb = hs + ((size_t)arow * TSTEPS + (t - 1)) * HID + w * 256 + lk;
      Frag8 a[8];
      unsigned int valid = 0;  // wave-uniform bitmask of sentinel-free fragments
      do {
        #pragma unroll
        for (int kc = 0; kc < 8; ++kc) {
          if (!(valid & (1u << kc))) {
            asm volatile("global_load_dwordx4 %0, %1, off offset:%2 sc0 sc1"
                         : "=v"(a[kc].d) : "v"(hb), "n"(kc * 64));
          }
        }
        // drains poll loads AND the previous step's h-store / xp-prefetch (overlapped)
        asm volatile("s_waitcnt vmcnt(0)" ::: "memory");
        __builtin_amdgcn_sched_barrier(0);  // rule #18
        #pragma unroll
        for (int kc = 0; kc < 8; ++kc) {
          if (!(valid & (1u << kc))) {
            unsigned int mv = min(min(a[kc].d[0] ^ SENT, a[kc].d[1] ^ SENT),
                                  min(a[kc].d[2] ^ SENT, a[kc].d[3] ^ SENT));
            if (__all(mv != 0u)) {
              valid |= (1u << kc);
              #pragma unroll
              for (int jt = 0; jt < 4; ++jt)
                acc[jt] = __builtin_amdgcn_mfma_f32_16x16x32_bf16(a[kc].b, Bw[jt][kc].b, acc[jt], 0, 0, 0);
            }
          }
        }
      } while (valid != 0xFFu);
    }

    // cross-wave K-reduction via LDS
    #pragma unroll
    for (int jt = 0; jt < 4; ++jt)
      #pragma unroll
      for (int r = 0; r < 4; ++r)
        red[w][jt][(l >> 4) * 4 + r][l15] = acc[jt][r];
    __syncthreads();

    unsigned int packed = 0;
    if (tid < 256) {
      float s0 = __uint_as_float(xr[0]), s1 = __uint_as_float(xr[1]);
      #pragma unroll
      for (int wv = 0; wv < 8; ++wv) {
        s0 += red[wv][jt_e][om][col];
        s1 += red[wv][jt_e][om][col + 1];
      }
      packed = (unsigned int)f2bf(tanh_fast(s0)) | ((unsigned int)f2bf(tanh_fast(s1)) << 16);
    }
    __syncthreads();  // red[] reuse guard (epilogue reads done above)

    if (tid < 256) {
      // deferred store: issued after the barrier; ACK drains in next step's poll vmcnt(0)
      unsigned int* hp = (unsigned int*)(hs + ((size_t)om * TSTEPS + t) * HID + jbase + oj2);
      asm volatile("global_store_dword %0, %1, off sc0 sc1" :: "v"(hp), "v"(packed) : "memory");
      if (t + 1 < TSTEPS) {  // xp prefetch for t+1; waited in next poll's vmcnt(0)
        const float* xq = xp + ((size_t)(t + 1) * BB + om) * HID + jbase + oj2;
        asm volatile("global_load_dwordx2 %0, %1, off" : "=v"(xr) : "v"(xq));
      }
    }
  }
}

extern "C" void kernel_launch(void* const* d_in, const int* in_sizes, int n_in,
                              void* d_out, int out_size, void* d_ws, size_t ws_size,
                              hipStream_t stream)
{
  (void)in_sizes; (void)n_in; (void)out_size; (void)ws_size;
  const float* x    = (const float*)d_in[0];
  const float* Wih  = (const float*)d_in[1];
  const float* bih  = (const float*)d_in[2];
  const float* Whh  = (const float*)d_in[3];
  const float* bhh  = (const float*)d_in[4];
  const float* Wout = (const float*)d_in[5];
  const float* bout = (const float*)d_in[6];
  float* out = (float*)d_out;

  char* ws = (char*)d_ws;
  float* xp          = (float*)(ws);                                // [512][8][2048] fp32, 32 MiB
  unsigned short* hs = (unsigned short*)(ws + (size_t)(32 << 20));  // [8][512][2048] bf16, 16 MiB

  // Phase 0: sentinel-fill hs
  sentinel_kernel<<<dim3(4096), 256, 0, stream>>>((u32x4*)hs);
  // Phase 1: xp = x @ W_ih^T + b_ih + b_hh
  gemm_kernel<0><<<dim3(64, 32), 256, 0, stream>>>(x, Wih, bih, bhh, xp, IN_K, HID);
  // Phase 2: barrier-free sequential scan (deferred stores)
  scan_kernel<<<dim3(NWG), 512, 0, stream>>>(Whh, xp, hs);
  // Phase 3: out = hs @ W_out^T + b_out
  gemm_kernel<1><<<dim3(64, 2), 256, 0, stream>>>(hs, Wout, bout, nullptr, out, HID, OUTN);
}